// Round 1
// baseline (736.679 us; speedup 1.0000x reference)
//
#include <hip/hip_runtime.h>

// Encoder: B=512, T=128, N=128, H=256
// Phases:
//  k_pre : pre'[b][i][tau] = C2L*(sum_t data[b][t][i]*W1[t][tau] + b1[tau])
//  k_xw  : xw[t][b][j]     = sum_i data[b][t][i]*Wx[i][j] + b[j]
//  k_rnn : h_t = tanh(xw + h@Wh)   (per-block recurrence, Wh in VGPRs as f16)
//  k_q   : q'[t][b][tau]   = C2L*(sum_k H[t][b][k]*W2[k][tau] + b2[tau])
//  k_attn: e[i] = sum_tau (-2Wv[tau]) * rcp(exp2(pre'+q')+1)  (== Wv.tanh up to
//          a softmax-invariant constant), softmax over i, out = data*alpha.
// Workspace layout (floats): pre 8388608 | xw/Q 16777216 | H 16777216
//   => needs 167,772,160 bytes of d_ws.

#define C2L 2.8853900817779268f   // 2*log2(e)
#define L2E 1.4426950408889634f   // log2(e)

typedef _Float16 hf;
typedef _Float16 hf2 __attribute__((ext_vector_type(2)));

__device__ __forceinline__ float fast_exp2(float x){
#if __has_builtin(__builtin_amdgcn_exp2f)
  return __builtin_amdgcn_exp2f(x);
#else
  return exp2f(x);
#endif
}
__device__ __forceinline__ float fast_rcp(float x){
#if __has_builtin(__builtin_amdgcn_rcpf)
  return __builtin_amdgcn_rcpf(x);
#else
  return 1.f/x;
#endif
}
__device__ __forceinline__ float dot2f(hf2 a, hf2 b, float c){
#if __has_builtin(__builtin_amdgcn_fdot2)
  return __builtin_amdgcn_fdot2(a, b, c, false);
#else
  return c + (float)a.x*(float)b.x + (float)a.y*(float)b.y;
#endif
}

// ---------------- Phase A1: pre' ----------------
// grid 512 (one block per b), 256 threads, LDS 64KB, K tiled by 64.
__global__ __launch_bounds__(256) void k_pre(const float* __restrict__ data,
    const float* __restrict__ W1, const float* __restrict__ bias1,
    float* __restrict__ pre){
  __shared__ alignas(16) float ds[64*128];   // data[b] tile: [t][i]
  __shared__ alignas(16) float ww[64*128];   // W1 tile: [t][tau]
  const int b = blockIdx.x, tid = threadIdx.x;
  const int tx = tid & 15, ty = tid >> 4;
  const int i0 = ty*8, u0 = tx*8;            // i rows, tau cols
  float acc[8][8];
  #pragma unroll
  for (int p=0;p<8;p++){
    #pragma unroll
    for (int q=0;q<8;q++) acc[p][q]=0.f;
  }
  const float* dblk = data + b*(128*128);
  for (int kt=0; kt<2; kt++){
    __syncthreads();
    #pragma unroll
    for (int v=0; v<8; v++){
      int off = v*1024 + tid*4;
      *(float4*)&ds[off] = *(const float4*)&dblk[kt*8192 + off];
      *(float4*)&ww[off] = *(const float4*)&W1[kt*8192 + off];
    }
    __syncthreads();
    for (int t=0;t<64;t++){
      float4 a0 = *(float4*)&ds[t*128 + i0];
      float4 a1 = *(float4*)&ds[t*128 + i0+4];
      float4 w0 = *(float4*)&ww[t*128 + u0];
      float4 w1 = *(float4*)&ww[t*128 + u0+4];
      float a[8] = {a0.x,a0.y,a0.z,a0.w,a1.x,a1.y,a1.z,a1.w};
      float w[8] = {w0.x,w0.y,w0.z,w0.w,w1.x,w1.y,w1.z,w1.w};
      #pragma unroll
      for(int p=0;p<8;p++){
        #pragma unroll
        for(int q=0;q<8;q++) acc[p][q] = fmaf(a[p], w[q], acc[p][q]);
      }
    }
  }
  float bs[8];
  #pragma unroll
  for(int q=0;q<8;q++) bs[q] = bias1[u0+q];
  float* po = pre + b*(128*128) + i0*128 + u0;
  #pragma unroll
  for(int p=0;p<8;p++){
    float4 o0 = {C2L*(acc[p][0]+bs[0]), C2L*(acc[p][1]+bs[1]),
                 C2L*(acc[p][2]+bs[2]), C2L*(acc[p][3]+bs[3])};
    float4 o1 = {C2L*(acc[p][4]+bs[4]), C2L*(acc[p][5]+bs[5]),
                 C2L*(acc[p][6]+bs[6]), C2L*(acc[p][7]+bs[7])};
    *(float4*)&po[p*128]   = o0;
    *(float4*)&po[p*128+4] = o1;
  }
}

// ---------------- Phase A2: xw ----------------
// grid 2048 (32 rows of (b,t) each), 256 threads. K=128 tiled by 32.
__global__ __launch_bounds__(256) void k_xw(const float* __restrict__ data,
    const float* __restrict__ Wx, const float* __restrict__ bias,
    float* __restrict__ xw){
  __shared__ alignas(16) float a_s[32*36];
  __shared__ alignas(16) float w_s[32*260];
  const int tid = threadIdx.x;
  const int row0 = blockIdx.x*32;            // row = b*128 + t
  const int tx = tid & 31, ty = tid >> 5;    // j0 = tx*8, rows ty*4..+4
  float acc[4][8];
  #pragma unroll
  for (int p=0;p<4;p++){
    #pragma unroll
    for (int q=0;q<8;q++) acc[p][q]=0.f;
  }
  for (int kt=0; kt<4; kt++){
    __syncthreads();
    { int rr = tid>>3, c4 = (tid&7)*4;
      *(float4*)&a_s[rr*36 + c4] = *(const float4*)&data[(row0+rr)*128 + kt*32 + c4]; }
    { int kk = tid>>3, c4 = (tid&7)*4;
      #pragma unroll
      for (int v=0; v<8; v++){
        int c = c4 + v*32;
        *(float4*)&w_s[kk*260 + c] = *(const float4*)&Wx[(kt*32+kk)*256 + c];
      } }
    __syncthreads();
    for (int k=0;k<32;k++){
      float a[4];
      #pragma unroll
      for(int p=0;p<4;p++) a[p] = a_s[(ty*4+p)*36 + k];
      float4 w0 = *(float4*)&w_s[k*260 + tx*8];
      float4 w1 = *(float4*)&w_s[k*260 + tx*8+4];
      float w[8] = {w0.x,w0.y,w0.z,w0.w,w1.x,w1.y,w1.z,w1.w};
      #pragma unroll
      for(int p=0;p<4;p++){
        #pragma unroll
        for(int q=0;q<8;q++) acc[p][q] = fmaf(a[p], w[q], acc[p][q]);
      }
    }
  }
  float bs[8];
  #pragma unroll
  for(int q=0;q<8;q++) bs[q] = bias[tx*8+q];
  #pragma unroll
  for(int p=0;p<4;p++){
    int r = row0 + ty*4 + p;
    int bi = r >> 7, ti = r & 127;
    float* o = xw + (ti*512 + bi)*256 + tx*8;
    float4 o0 = {acc[p][0]+bs[0], acc[p][1]+bs[1], acc[p][2]+bs[2], acc[p][3]+bs[3]};
    float4 o1 = {acc[p][4]+bs[4], acc[p][5]+bs[5], acc[p][6]+bs[6], acc[p][7]+bs[7]};
    *(float4*)&o[0] = o0;
    *(float4*)&o[4] = o1;
  }
}

// ---------------- Phase B: recurrence ----------------
// grid 256 blocks x 512 threads; block handles batches 2*blk, 2*blk+1.
// Thread (j, beta) holds Wh[:, j] as 128 packed f16 pairs in VGPRs.
__global__ __launch_bounds__(512) void k_rnn(const float* __restrict__ h0,
    const float* __restrict__ Wh, const float* __restrict__ xw,
    float* __restrict__ H){
  __shared__ alignas(16) hf h_s[2][256];
  const int tid = threadIdx.x;
  const int j = tid & 255, beta = tid >> 8;
  const int bb = blockIdx.x*2 + beta;
  hf2 wreg[128];
  #pragma unroll
  for (int m=0;m<128;m++){
    float w0 = Wh[(2*m)*256 + j];
    float w1 = Wh[(2*m+1)*256 + j];
    wreg[m] = (hf2){(hf)w0, (hf)w1};
  }
  h_s[beta][j] = (hf)h0[bb*256 + j];
  __syncthreads();
  for (int t=0;t<128;t++){
    float z = xw[(t*512 + bb)*256 + j];
    const hf2* hp = (const hf2*)(&h_s[beta][0]);
    float a0=0.f,a1=0.f,a2=0.f,a3=0.f;
    #pragma unroll
    for (int m=0;m<128;m+=4){
      a0 = dot2f(wreg[m],   hp[m],   a0);
      a1 = dot2f(wreg[m+1], hp[m+1], a1);
      a2 = dot2f(wreg[m+2], hp[m+2], a2);
      a3 = dot2f(wreg[m+3], hp[m+3], a3);
    }
    float v = z + ((a0+a1)+(a2+a3));
    float e2 = fast_exp2(v*C2L);
    float hn = 1.f - 2.f*fast_rcp(e2 + 1.f);
    H[(t*512+bb)*256 + j] = hn;
    __syncthreads();
    h_s[beta][j] = (hf)hn;
    __syncthreads();
  }
}

// ---------------- Phase Q: q' ----------------
// grid 2048 (32 rows of (t,b) each), 256 threads, K=256 tiled by 32.
__global__ __launch_bounds__(256) void k_q(const float* __restrict__ H,
    const float* __restrict__ W2, const float* __restrict__ b2,
    float* __restrict__ Q){
  __shared__ alignas(16) float a_s[32*36];
  __shared__ alignas(16) float w_s[32*132];
  const int tid = threadIdx.x;
  const int row0 = blockIdx.x*32;            // row r = t*512+b
  const int tx = tid & 15, ty = tid >> 4;    // tau0 = tx*8, rows ty*2
  float acc[2][8];
  #pragma unroll
  for (int p=0;p<2;p++){
    #pragma unroll
    for (int q=0;q<8;q++) acc[p][q]=0.f;
  }
  for (int kt=0; kt<8; kt++){
    __syncthreads();
    { int rr = tid>>3, c4 = (tid&7)*4;
      *(float4*)&a_s[rr*36 + c4] = *(const float4*)&H[(row0+rr)*256 + kt*32 + c4]; }
    { int kk = tid>>3, c4 = (tid&7)*4;
      #pragma unroll
      for (int v=0; v<4; v++){
        int c = c4 + v*32;
        *(float4*)&w_s[kk*132 + c] = *(const float4*)&W2[(kt*32+kk)*128 + c];
      } }
    __syncthreads();
    for (int k=0;k<32;k++){
      float ar0 = a_s[(ty*2)*36 + k];
      float ar1 = a_s[(ty*2+1)*36 + k];
      float4 w0 = *(float4*)&w_s[k*132 + tx*8];
      float4 w1 = *(float4*)&w_s[k*132 + tx*8+4];
      float w[8] = {w0.x,w0.y,w0.z,w0.w,w1.x,w1.y,w1.z,w1.w};
      #pragma unroll
      for(int q=0;q<8;q++){
        acc[0][q] = fmaf(ar0, w[q], acc[0][q]);
        acc[1][q] = fmaf(ar1, w[q], acc[1][q]);
      }
    }
  }
  float bs[8];
  #pragma unroll
  for(int q=0;q<8;q++) bs[q] = b2[tx*8+q];
  #pragma unroll
  for(int p=0;p<2;p++){
    int r = row0 + ty*2 + p;
    float* o = Q + r*128 + tx*8;
    float4 o0 = {C2L*(acc[p][0]+bs[0]), C2L*(acc[p][1]+bs[1]),
                 C2L*(acc[p][2]+bs[2]), C2L*(acc[p][3]+bs[3])};
    float4 o1 = {C2L*(acc[p][4]+bs[4]), C2L*(acc[p][5]+bs[5]),
                 C2L*(acc[p][6]+bs[6]), C2L*(acc[p][7]+bs[7])};
    *(float4*)&o[0] = o0;
    *(float4*)&o[4] = o1;
  }
}

// ---------------- Phase C: attention + softmax + scale ----------------
// grid 512 (one block per b), 256 threads. pre[b] slab cached in LDS as f16.
__global__ __launch_bounds__(256) void k_attn(const float* __restrict__ pre,
    const float* __restrict__ Qm, const float* __restrict__ Wv,
    const float* __restrict__ data, float* __restrict__ out){
  __shared__ alignas(16) hf2 preh[128*65];   // [i][tau/2], stride 65 (pad)
  __shared__ alignas(16) float qs[128];
  __shared__ alignas(16) float epart[2][128];
  __shared__ float red[4];
  const int b = blockIdx.x, tid = threadIdx.x;
  const int i = tid & 127, hl = tid >> 7;
  const float* pb = pre + b*(128*128);
  #pragma unroll
  for (int v=0; v<16; v++){
    int gidx = v*1024 + tid*4;
    float4 f = *(const float4*)&pb[gidx];
    int ii = gidx >> 7, tau = gidx & 127;
    preh[ii*65 + (tau>>1)]     = (hf2){(hf)f.x,(hf)f.y};
    preh[ii*65 + (tau>>1) + 1] = (hf2){(hf)f.z,(hf)f.w};
  }
  float2 wvr[32];
  #pragma unroll
  for (int m=0;m<32;m++){
    wvr[m].x = -2.f*Wv[hl*64 + 2*m];
    wvr[m].y = -2.f*Wv[hl*64 + 2*m+1];
  }
  __syncthreads();
  for (int t=0;t<128;t++){
    if (tid < 128) qs[tid] = Qm[(t*512 + b)*128 + tid];
    __syncthreads();
    const hf2* prow = &preh[i*65 + hl*32];
    const float2* q2 = ((const float2*)qs) + hl*32;
    float acc = 0.f;
    #pragma unroll
    for (int m=0;m<32;m++){
      hf2 ph = prow[m];
      float2 qq = q2[m];
      float s0 = (float)ph.x + qq.x;
      float s1 = (float)ph.y + qq.y;
      float r0 = fast_rcp(fast_exp2(s0) + 1.f);
      float r1 = fast_rcp(fast_exp2(s1) + 1.f);
      acc = fmaf(wvr[m].x, r0, acc);
      acc = fmaf(wvr[m].y, r1, acc);
    }
    epart[hl][i] = acc;
    __syncthreads();
    float e = 0.f, p = 0.f;
    if (tid < 128){
      e = epart[0][i] + epart[1][i];
      float mx = e;
      #pragma unroll
      for (int off=32; off; off>>=1) mx = fmaxf(mx, __shfl_xor(mx, off));
      if ((tid & 63) == 0) red[tid>>6] = mx;
    }
    __syncthreads();
    float mg = fmaxf(red[0], red[1]);
    if (tid < 128){
      p = fast_exp2((e - mg)*L2E);
      float sm = p;
      #pragma unroll
      for (int off=32; off; off>>=1) sm += __shfl_xor(sm, off);
      if ((tid & 63) == 0) red[2 + (tid>>6)] = sm;
    }
    __syncthreads();
    float ssum = red[2] + red[3];
    if (tid < 128){
      float alpha = p * fast_rcp(ssum);
      int base = (t*512 + b)*128 + i;
      out[base] = data[base]*alpha;
    }
    __syncthreads();
  }
}

extern "C" void kernel_launch(void* const* d_in, const int* in_sizes, int n_in,
                              void* d_out, int out_size, void* d_ws, size_t ws_size,
                              hipStream_t stream) {
  const float* data = (const float*)d_in[0];
  const float* h0   = (const float*)d_in[1];
  const float* Wx   = (const float*)d_in[2];
  const float* Wh   = (const float*)d_in[3];
  const float* bb   = (const float*)d_in[4];
  const float* W1   = (const float*)d_in[5];
  const float* b1   = (const float*)d_in[6];
  const float* W2   = (const float*)d_in[7];
  const float* b2   = (const float*)d_in[8];
  const float* Wv   = (const float*)d_in[9];
  // d_in[10] = bv: softmax-invariant constant, dropped. d_in[11] = n (128).
  float* wsp = (float*)d_ws;
  float* pre = wsp;                         //  8,388,608 f
  float* xwQ = wsp + 8388608;               // 16,777,216 f (xw, then reused as Q)
  float* H   = wsp + 8388608 + 16777216;    // 16,777,216 f
  float* out = (float*)d_out;

  hipLaunchKernelGGL(k_pre,  dim3(512),  dim3(256), 0, stream, data, W1, b1, pre);
  hipLaunchKernelGGL(k_xw,   dim3(2048), dim3(256), 0, stream, data, Wx, bb, xwQ);
  hipLaunchKernelGGL(k_rnn,  dim3(256),  dim3(512), 0, stream, h0, Wh, xwQ, H);
  hipLaunchKernelGGL(k_q,    dim3(2048), dim3(256), 0, stream, H, W2, b2, xwQ);
  hipLaunchKernelGGL(k_attn, dim3(512),  dim3(256), 0, stream, pre, xwQ, Wv, data, out);
}

// Round 2
// 521.863 us; speedup vs baseline: 1.4116x; 1.4116x over previous
//
#include <hip/hip_runtime.h>

// Encoder: B=512, T=128, N=128, H=256
// Round 2: exp2 hoisted out of attention inner loop via exp2(a+b)=exp2(a)*exp2(b).
//  k_pre : P[b][i][tau] = exp2( C2L*(sum_t data[b][t][i]*W1[t][tau] + b1[tau]) )
//  k_xw  : xw[t][b][j]  = sum_i data[b][t][i]*Wx[i][j] + b[j]
//  k_rnn : h_t = tanh(xw + h@Wh)   (per-block recurrence, Wh in VGPRs as f16)
//  k_q   : Q[t][b][tau] = exp2( C2L*(sum_k H[t][b][k]*W2[k][tau] + b2[tau]) )
//  k_attn: tanh-term = 1 - 2*rcp(P*Q+1); e_i = sum_tau (-2wv)*rcp(P*Q+1) + const
//          (const is softmax-invariant, dropped); softmax over i without max
//          subtraction (|e| <= sum|wv| ~ 5, no overflow); out = data*alpha.
// Workspace (floats): P 8388608 | xw/Q 16777216 | H 16777216  => 167,772,160 B.

#define C2L 2.8853900817779268f   // 2*log2(e)
#define L2E 1.4426950408889634f   // log2(e)

typedef _Float16 hf;
typedef _Float16 hf2 __attribute__((ext_vector_type(2)));

__device__ __forceinline__ float fast_exp2(float x){
#if __has_builtin(__builtin_amdgcn_exp2f)
  return __builtin_amdgcn_exp2f(x);
#else
  return exp2f(x);
#endif
}
__device__ __forceinline__ float fast_rcp(float x){
#if __has_builtin(__builtin_amdgcn_rcpf)
  return __builtin_amdgcn_rcpf(x);
#else
  return 1.f/x;
#endif
}
__device__ __forceinline__ float dot2f(hf2 a, hf2 b, float c){
#if __has_builtin(__builtin_amdgcn_fdot2)
  return __builtin_amdgcn_fdot2(a, b, c, false);
#else
  return c + (float)a.x*(float)b.x + (float)a.y*(float)b.y;
#endif
}

// ---------------- Phase A1: P ----------------
// grid 512 (one block per b), 256 threads, LDS 64KB, K tiled by 64.
__global__ __launch_bounds__(256) void k_pre(const float* __restrict__ data,
    const float* __restrict__ W1, const float* __restrict__ bias1,
    float* __restrict__ P){
  __shared__ alignas(16) float ds[64*128];   // data[b] tile: [t][i]
  __shared__ alignas(16) float ww[64*128];   // W1 tile: [t][tau]
  const int b = blockIdx.x, tid = threadIdx.x;
  const int tx = tid & 15, ty = tid >> 4;
  const int i0 = ty*8, u0 = tx*8;            // i rows, tau cols
  float acc[8][8];
  #pragma unroll
  for (int p=0;p<8;p++){
    #pragma unroll
    for (int q=0;q<8;q++) acc[p][q]=0.f;
  }
  const float* dblk = data + b*(128*128);
  for (int kt=0; kt<2; kt++){
    __syncthreads();
    #pragma unroll
    for (int v=0; v<8; v++){
      int off = v*1024 + tid*4;
      *(float4*)&ds[off] = *(const float4*)&dblk[kt*8192 + off];
      *(float4*)&ww[off] = *(const float4*)&W1[kt*8192 + off];
    }
    __syncthreads();
    for (int t=0;t<64;t++){
      float4 a0 = *(float4*)&ds[t*128 + i0];
      float4 a1 = *(float4*)&ds[t*128 + i0+4];
      float4 w0 = *(float4*)&ww[t*128 + u0];
      float4 w1 = *(float4*)&ww[t*128 + u0+4];
      float a[8] = {a0.x,a0.y,a0.z,a0.w,a1.x,a1.y,a1.z,a1.w};
      float w[8] = {w0.x,w0.y,w0.z,w0.w,w1.x,w1.y,w1.z,w1.w};
      #pragma unroll
      for(int p=0;p<8;p++){
        #pragma unroll
        for(int q=0;q<8;q++) acc[p][q] = fmaf(a[p], w[q], acc[p][q]);
      }
    }
  }
  float bs[8];
  #pragma unroll
  for(int q=0;q<8;q++) bs[q] = bias1[u0+q];
  float* po = P + b*(128*128) + i0*128 + u0;
  #pragma unroll
  for(int p=0;p<8;p++){
    float4 o0 = {fast_exp2(C2L*(acc[p][0]+bs[0])), fast_exp2(C2L*(acc[p][1]+bs[1])),
                 fast_exp2(C2L*(acc[p][2]+bs[2])), fast_exp2(C2L*(acc[p][3]+bs[3]))};
    float4 o1 = {fast_exp2(C2L*(acc[p][4]+bs[4])), fast_exp2(C2L*(acc[p][5]+bs[5])),
                 fast_exp2(C2L*(acc[p][6]+bs[6])), fast_exp2(C2L*(acc[p][7]+bs[7]))};
    *(float4*)&po[p*128]   = o0;
    *(float4*)&po[p*128+4] = o1;
  }
}

// ---------------- Phase A2: xw ----------------
// grid 2048 (32 rows of (b,t) each), 256 threads. K=128 tiled by 32.
__global__ __launch_bounds__(256) void k_xw(const float* __restrict__ data,
    const float* __restrict__ Wx, const float* __restrict__ bias,
    float* __restrict__ xw){
  __shared__ alignas(16) float a_s[32*36];
  __shared__ alignas(16) float w_s[32*260];
  const int tid = threadIdx.x;
  const int row0 = blockIdx.x*32;            // row = b*128 + t
  const int tx = tid & 31, ty = tid >> 5;    // j0 = tx*8, rows ty*4..+4
  float acc[4][8];
  #pragma unroll
  for (int p=0;p<4;p++){
    #pragma unroll
    for (int q=0;q<8;q++) acc[p][q]=0.f;
  }
  for (int kt=0; kt<4; kt++){
    __syncthreads();
    { int rr = tid>>3, c4 = (tid&7)*4;
      *(float4*)&a_s[rr*36 + c4] = *(const float4*)&data[(row0+rr)*128 + kt*32 + c4]; }
    { int kk = tid>>3, c4 = (tid&7)*4;
      #pragma unroll
      for (int v=0; v<8; v++){
        int c = c4 + v*32;
        *(float4*)&w_s[kk*260 + c] = *(const float4*)&Wx[(kt*32+kk)*256 + c];
      } }
    __syncthreads();
    for (int k=0;k<32;k++){
      float a[4];
      #pragma unroll
      for(int p=0;p<4;p++) a[p] = a_s[(ty*4+p)*36 + k];
      float4 w0 = *(float4*)&w_s[k*260 + tx*8];
      float4 w1 = *(float4*)&w_s[k*260 + tx*8+4];
      float w[8] = {w0.x,w0.y,w0.z,w0.w,w1.x,w1.y,w1.z,w1.w};
      #pragma unroll
      for(int p=0;p<4;p++){
        #pragma unroll
        for(int q=0;q<8;q++) acc[p][q] = fmaf(a[p], w[q], acc[p][q]);
      }
    }
  }
  float bs[8];
  #pragma unroll
  for(int q=0;q<8;q++) bs[q] = bias[tx*8+q];
  #pragma unroll
  for(int p=0;p<4;p++){
    int r = row0 + ty*4 + p;
    int bi = r >> 7, ti = r & 127;
    float* o = xw + (ti*512 + bi)*256 + tx*8;
    float4 o0 = {acc[p][0]+bs[0], acc[p][1]+bs[1], acc[p][2]+bs[2], acc[p][3]+bs[3]};
    float4 o1 = {acc[p][4]+bs[4], acc[p][5]+bs[5], acc[p][6]+bs[6], acc[p][7]+bs[7]};
    *(float4*)&o[0] = o0;
    *(float4*)&o[4] = o1;
  }
}

// ---------------- Phase B: recurrence ----------------
// grid 256 blocks x 512 threads; block handles batches 2*blk, 2*blk+1.
// Thread (j, beta) holds Wh[:, j] as 128 packed f16 pairs in VGPRs.
// Double-buffered h in LDS: 1 barrier per step.
__global__ __launch_bounds__(512) void k_rnn(const float* __restrict__ h0,
    const float* __restrict__ Wh, const float* __restrict__ xw,
    float* __restrict__ H){
  __shared__ alignas(16) hf h_s[2][2][256];  // [parity][beta][j]
  const int tid = threadIdx.x;
  const int j = tid & 255, beta = tid >> 8;
  const int bb = blockIdx.x*2 + beta;
  hf2 wreg[128];
  #pragma unroll
  for (int m=0;m<128;m++){
    float w0 = Wh[(2*m)*256 + j];
    float w1 = Wh[(2*m+1)*256 + j];
    wreg[m] = (hf2){(hf)w0, (hf)w1};
  }
  h_s[0][beta][j] = (hf)h0[bb*256 + j];
  __syncthreads();
  for (int t=0;t<128;t++){
    int p = t & 1;
    float z = xw[(t*512 + bb)*256 + j];
    const hf2* hp = (const hf2*)(&h_s[p][beta][0]);
    float a0=0.f,a1=0.f,a2=0.f,a3=0.f;
    #pragma unroll
    for (int m=0;m<128;m+=4){
      a0 = dot2f(wreg[m],   hp[m],   a0);
      a1 = dot2f(wreg[m+1], hp[m+1], a1);
      a2 = dot2f(wreg[m+2], hp[m+2], a2);
      a3 = dot2f(wreg[m+3], hp[m+3], a3);
    }
    float v = z + ((a0+a1)+(a2+a3));
    float e2 = fast_exp2(v*C2L);
    float hn = 1.f - 2.f*fast_rcp(e2 + 1.f);
    H[(t*512+bb)*256 + j] = hn;
    h_s[p^1][beta][j] = (hf)hn;
    __syncthreads();
  }
}

// ---------------- Phase Q: Q ----------------
// grid 2048 (32 rows of (t,b) each), 256 threads, K=256 tiled by 32.
__global__ __launch_bounds__(256) void k_q(const float* __restrict__ H,
    const float* __restrict__ W2, const float* __restrict__ b2,
    float* __restrict__ Q){
  __shared__ alignas(16) float a_s[32*36];
  __shared__ alignas(16) float w_s[32*132];
  const int tid = threadIdx.x;
  const int row0 = blockIdx.x*32;            // row r = t*512+b
  const int tx = tid & 15, ty = tid >> 4;    // tau0 = tx*8, rows ty*2
  float acc[2][8];
  #pragma unroll
  for (int p=0;p<2;p++){
    #pragma unroll
    for (int q=0;q<8;q++) acc[p][q]=0.f;
  }
  for (int kt=0; kt<8; kt++){
    __syncthreads();
    { int rr = tid>>3, c4 = (tid&7)*4;
      *(float4*)&a_s[rr*36 + c4] = *(const float4*)&H[(row0+rr)*256 + kt*32 + c4]; }
    { int kk = tid>>3, c4 = (tid&7)*4;
      #pragma unroll
      for (int v=0; v<4; v++){
        int c = c4 + v*32;
        *(float4*)&w_s[kk*132 + c] = *(const float4*)&W2[(kt*32+kk)*128 + c];
      } }
    __syncthreads();
    for (int k=0;k<32;k++){
      float ar0 = a_s[(ty*2)*36 + k];
      float ar1 = a_s[(ty*2+1)*36 + k];
      float4 w0 = *(float4*)&w_s[k*132 + tx*8];
      float4 w1 = *(float4*)&w_s[k*132 + tx*8+4];
      float w[8] = {w0.x,w0.y,w0.z,w0.w,w1.x,w1.y,w1.z,w1.w};
      #pragma unroll
      for(int q=0;q<8;q++){
        acc[0][q] = fmaf(ar0, w[q], acc[0][q]);
        acc[1][q] = fmaf(ar1, w[q], acc[1][q]);
      }
    }
  }
  float bs[8];
  #pragma unroll
  for(int q=0;q<8;q++) bs[q] = b2[tx*8+q];
  #pragma unroll
  for(int p=0;p<2;p++){
    int r = row0 + ty*2 + p;
    float* o = Q + r*128 + tx*8;
    float4 o0 = {fast_exp2(C2L*(acc[p][0]+bs[0])), fast_exp2(C2L*(acc[p][1]+bs[1])),
                 fast_exp2(C2L*(acc[p][2]+bs[2])), fast_exp2(C2L*(acc[p][3]+bs[3]))};
    float4 o1 = {fast_exp2(C2L*(acc[p][4]+bs[4])), fast_exp2(C2L*(acc[p][5]+bs[5])),
                 fast_exp2(C2L*(acc[p][6]+bs[6])), fast_exp2(C2L*(acc[p][7]+bs[7]))};
    *(float4*)&o[0] = o0;
    *(float4*)&o[4] = o1;
  }
}

// ---------------- Phase C: attention + softmax + scale ----------------
// grid (512 b, 4 t-tiles), 256 threads. P row halves in registers (64 f32),
// Q tile (32 t) in LDS. Inner element: rcp(fma(P,Q,1)) + fma. No max in
// softmax (|e| <= sum|wv| ~ 5). 2 barriers per 2 timesteps (parity buffers).
__global__ __launch_bounds__(256, 4) void k_attn(const float* __restrict__ P,
    const float* __restrict__ Qm, const float* __restrict__ Wv,
    const float* __restrict__ data, float* __restrict__ out){
  __shared__ alignas(16) float qs[32*128];        // [tt][tau] 16KB
  __shared__ alignas(16) float wvs[128];
  __shared__ alignas(16) float epart[2][2][2][128]; // [parity][tpar][hl][i]
  __shared__ float red[2][2][2];                    // [parity][tpar][half]
  const int b = blockIdx.x, tile = blockIdx.y;
  const int tid = threadIdx.x;
  const int i = tid & 127, hl = tid >> 7;
  const int t0 = tile*32;
  if (tid < 128) wvs[tid] = -2.f*Wv[tid];
  #pragma unroll
  for (int v=0; v<4; v++){
    int flat = v*1024 + tid*4;
    int tt = flat >> 7, c = flat & 127;
    *(float4*)&qs[flat] = *(const float4*)&Qm[((t0+tt)*512 + b)*128 + c];
  }
  float4 p4[16];
  const float* prow = P + b*16384 + i*128 + hl*64;
  #pragma unroll
  for (int v=0; v<16; v++) p4[v] = *(const float4*)&prow[v*4];
  __syncthreads();
  for (int tp=0; tp<16; tp++){
    const int pp = tp & 1;
    const float* q0r = &qs[(2*tp)*128   + hl*64];
    const float* q1r = &qs[(2*tp+1)*128 + hl*64];
    const float* wvr = &wvs[hl*64];
    float4 acc0 = {0.f,0.f,0.f,0.f}, acc1 = {0.f,0.f,0.f,0.f};
    #pragma unroll
    for (int m=0; m<16; m++){
      float4 Pv = p4[m];
      float4 q0 = *(const float4*)&q0r[m*4];
      float4 q1 = *(const float4*)&q1r[m*4];
      float4 wv = *(const float4*)&wvr[m*4];
      float r0x = fast_rcp(fmaf(Pv.x, q0.x, 1.f));
      float r0y = fast_rcp(fmaf(Pv.y, q0.y, 1.f));
      float r0z = fast_rcp(fmaf(Pv.z, q0.z, 1.f));
      float r0w = fast_rcp(fmaf(Pv.w, q0.w, 1.f));
      float r1x = fast_rcp(fmaf(Pv.x, q1.x, 1.f));
      float r1y = fast_rcp(fmaf(Pv.y, q1.y, 1.f));
      float r1z = fast_rcp(fmaf(Pv.z, q1.z, 1.f));
      float r1w = fast_rcp(fmaf(Pv.w, q1.w, 1.f));
      acc0.x = fmaf(wv.x, r0x, acc0.x);
      acc0.y = fmaf(wv.y, r0y, acc0.y);
      acc0.z = fmaf(wv.z, r0z, acc0.z);
      acc0.w = fmaf(wv.w, r0w, acc0.w);
      acc1.x = fmaf(wv.x, r1x, acc1.x);
      acc1.y = fmaf(wv.y, r1y, acc1.y);
      acc1.z = fmaf(wv.z, r1z, acc1.z);
      acc1.w = fmaf(wv.w, r1w, acc1.w);
    }
    epart[pp][0][hl][i] = (acc0.x+acc0.y)+(acc0.z+acc0.w);
    epart[pp][1][hl][i] = (acc1.x+acc1.y)+(acc1.z+acc1.w);
    __syncthreads();
    const int tpar = tid >> 7;
    float e = epart[pp][tpar][0][i] + epart[pp][tpar][1][i];
    float pexp = fast_exp2(e*L2E);
    float sm = pexp;
    #pragma unroll
    for (int off=32; off; off>>=1) sm += __shfl_xor(sm, off);
    if ((tid & 63) == 0) red[pp][tpar][(tid>>6)&1] = sm;
    __syncthreads();
    float ssum = red[pp][tpar][0] + red[pp][tpar][1];
    float alpha = pexp * fast_rcp(ssum);
    int t = t0 + 2*tp + tpar;
    int base = (t*512 + b)*128 + i;
    out[base] = data[base]*alpha;
  }
}

extern "C" void kernel_launch(void* const* d_in, const int* in_sizes, int n_in,
                              void* d_out, int out_size, void* d_ws, size_t ws_size,
                              hipStream_t stream) {
  const float* data = (const float*)d_in[0];
  const float* h0   = (const float*)d_in[1];
  const float* Wx   = (const float*)d_in[2];
  const float* Wh   = (const float*)d_in[3];
  const float* bb   = (const float*)d_in[4];
  const float* W1   = (const float*)d_in[5];
  const float* b1   = (const float*)d_in[6];
  const float* W2   = (const float*)d_in[7];
  const float* b2   = (const float*)d_in[8];
  const float* Wv   = (const float*)d_in[9];
  // d_in[10] = bv: softmax-invariant constant, dropped. d_in[11] = n (128).
  float* wsp = (float*)d_ws;
  float* P   = wsp;                         //  8,388,608 f
  float* xwQ = wsp + 8388608;               // 16,777,216 f (xw, then reused as Q)
  float* H   = wsp + 8388608 + 16777216;    // 16,777,216 f
  float* out = (float*)d_out;

  hipLaunchKernelGGL(k_pre,  dim3(512),     dim3(256), 0, stream, data, W1, b1, P);
  hipLaunchKernelGGL(k_xw,   dim3(2048),    dim3(256), 0, stream, data, Wx, bb, xwQ);
  hipLaunchKernelGGL(k_rnn,  dim3(256),     dim3(512), 0, stream, h0, Wh, xwQ, H);
  hipLaunchKernelGGL(k_q,    dim3(2048),    dim3(256), 0, stream, H, W2, b2, xwQ);
  hipLaunchKernelGGL(k_attn, dim3(512, 4),  dim3(256), 0, stream, P, xwQ, Wv, data, out);
}

// Round 3
// 399.207 us; speedup vs baseline: 1.8454x; 1.3072x over previous
//
#include <hip/hip_runtime.h>

// Encoder: B=512, T=128, N=128, H=256
// Round 3: f16 MFMA for the three GEMMs; H stored f16; weights pre-transposed.
//  k_prep_w: Wxt[256][128], W2t[128][256], W1t[128][128] (f16, [n][k] layouts)
//  k_gemm<K,MODE>: C = A @ Bt^T via mfma_f32_16x16x32_f16, Mt=64, Nt=128.
//    MODE0 (xw): A=data rows f32, out xw[(t*512+b)*256+j] = acc + bias
//    MODE1 (q) : A=Hb rows f16,  out Q[r*128+tau] = exp2(C2L*(acc+bias))
//    MODE2 (pre):A=data[b] transposed, out P[b][i][tau] = exp2(C2L*(acc+bias))
//  k_rnn : h_t = tanh(xw + h@Wh); Wh cols in VGPRs (f16 dot2); writes Hb f16
//  k_attn: e_i = sum_tau (-2wv)*rcp(P*Q+1) (+ softmax-invariant const, dropped);
//          softmax over i (no max needed, |e|<=sum|wv|~5); out = data*alpha.
// Workspace (f32 offsets): P 0 | xw/Q 8388608 | Hb(hf) 25165824 | wts(hf) 33554432
//   => 134,381,568 bytes.

#define C2L 2.8853900817779268f   // 2*log2(e)
#define L2E 1.4426950408889634f   // log2(e)

typedef _Float16 hf;
typedef _Float16 hf2 __attribute__((ext_vector_type(2)));
typedef _Float16 hf4 __attribute__((ext_vector_type(4)));
typedef _Float16 hf8 __attribute__((ext_vector_type(8)));
typedef float f32x4 __attribute__((ext_vector_type(4)));

__device__ __forceinline__ float fast_exp2(float x){
#if __has_builtin(__builtin_amdgcn_exp2f)
  return __builtin_amdgcn_exp2f(x);
#else
  return exp2f(x);
#endif
}
__device__ __forceinline__ float fast_rcp(float x){
#if __has_builtin(__builtin_amdgcn_rcpf)
  return __builtin_amdgcn_rcpf(x);
#else
  return 1.f/x;
#endif
}
__device__ __forceinline__ float dot2f(hf2 a, hf2 b, float c){
#if __has_builtin(__builtin_amdgcn_fdot2)
  return __builtin_amdgcn_fdot2(a, b, c, false);
#else
  return c + (float)a.x*(float)b.x + (float)a.y*(float)b.y;
#endif
}

// ---------------- weight prep: f32 [k][n] -> f16 [n][k] ----------------
__global__ __launch_bounds__(256) void k_prep_w(const float* __restrict__ Wx,
    const float* __restrict__ W2, const float* __restrict__ W1,
    hf* __restrict__ wts){
  int tid = blockIdx.x*256 + threadIdx.x;   // 320 blocks -> 81920 threads
  if (tid < 32768){                          // Wxt[n<256][k<128]
    int n = tid >> 7, k = tid & 127;
    wts[tid] = (hf)Wx[k*256 + n];
  } else if (tid < 65536){                   // W2t[n<128][k<256]
    int t2 = tid - 32768;
    int n = t2 >> 8, k = t2 & 255;
    wts[tid] = (hf)W2[k*128 + n];
  } else {                                   // W1t[n<128][k<128]
    int t3 = tid - 65536;
    int n = t3 >> 7, k = t3 & 127;
    wts[tid] = (hf)W1[k*128 + n];
  }
}

// ---------------- unified MFMA GEMM ----------------
// block = 256 thr (4 waves). Tile: M=64 (wave strip 16), N=128, K chunked by 128.
// LDS: As[64][136] + Bs[128][136] f16 = 52,224 B.
template<int K, int MODE>
__global__ __launch_bounds__(256) void k_gemm(const void* __restrict__ Asrc,
    const hf* __restrict__ Bt, const float* __restrict__ bias,
    float* __restrict__ Cout){
  constexpr int SA = 136;
  __shared__ alignas(16) hf As[64*SA];
  __shared__ alignas(16) hf Bs[128*SA];
  const int tid = threadIdx.x;
  const int w = tid >> 6, lane = tid & 63;
  const int c = lane & 15, q = lane >> 4;
  const int bx = blockIdx.x;
  const int col0 = (MODE==0) ? blockIdx.y*128 : 0;

  float br[8];
  #pragma unroll
  for (int ni=0; ni<8; ni++) br[ni] = bias[col0 + ni*16 + c];

  f32x4 acc[8];
  #pragma unroll
  for (int ni=0; ni<8; ni++) acc[ni] = (f32x4){0.f,0.f,0.f,0.f};

  for (int kc=0; kc<K/128; kc++){
    // ---- stage A chunk (64 rows x 128 k) ----
    if (MODE == 0){
      const float* A = (const float*)Asrc + (long)bx*64*128;
      #pragma unroll
      for (int v=0; v<8; v++){
        int f4 = v*256 + tid;
        int m = f4 >> 5, k4 = (f4 & 31)*4;
        float4 d = *(const float4*)&A[m*128 + k4];
        hf4 h = {(hf)d.x,(hf)d.y,(hf)d.z,(hf)d.w};
        *(hf4*)&As[m*SA + k4] = h;
      }
    } else if (MODE == 1){
      const hf* A = (const hf*)Asrc + (long)bx*64*256;
      #pragma unroll
      for (int v=0; v<4; v++){
        int f8 = v*256 + tid;
        int m = f8 >> 4, k8 = (f8 & 15)*8;
        *(hf8*)&As[m*SA + k8] = *(const hf8*)&A[m*256 + kc*128 + k8];
      }
    } else {
      const float* A = (const float*)Asrc + (long)(bx>>1)*16384;
      const int i0 = (bx & 1)*64;
      #pragma unroll
      for (int v=0; v<8; v++){
        int f4 = v*256 + tid;
        int t = f4 >> 4, i4 = (f4 & 15)*4;
        float4 d = *(const float4*)&A[t*128 + i0 + i4];
        As[(i4+0)*SA + t] = (hf)d.x;
        As[(i4+1)*SA + t] = (hf)d.y;
        As[(i4+2)*SA + t] = (hf)d.z;
        As[(i4+3)*SA + t] = (hf)d.w;
      }
    }
    // ---- stage B chunk (128 n x 128 k), Bt is f16 [n][K] ----
    #pragma unroll
    for (int v=0; v<8; v++){
      int f8 = v*256 + tid;
      int n = f8 >> 4, k8 = (f8 & 15)*8;
      *(hf8*)&Bs[n*SA + k8] = *(const hf8*)&Bt[(col0+n)*K + kc*128 + k8];
    }
    __syncthreads();
    // ---- MFMA ----
    #pragma unroll
    for (int kk=0; kk<4; kk++){
      hf8 a = *(const hf8*)&As[(w*16 + c)*SA + kk*32 + q*8];
      #pragma unroll
      for (int ni=0; ni<8; ni++){
        hf8 b = *(const hf8*)&Bs[(ni*16 + c)*SA + kk*32 + q*8];
        acc[ni] = __builtin_amdgcn_mfma_f32_16x16x32_f16(a, b, acc[ni], 0, 0, 0);
      }
    }
    __syncthreads();
  }
  // ---- epilogue ----
  #pragma unroll
  for (int ni=0; ni<8; ni++){
    #pragma unroll
    for (int r=0; r<4; r++){
      int rloc = w*16 + q*4 + r;
      int col = col0 + ni*16 + c;
      float val = acc[ni][r] + br[ni];
      int addr;
      if (MODE == 0){
        int R = bx*64 + rloc;
        int b_ = R >> 7, t_ = R & 127;
        addr = (t_*512 + b_)*256 + col;
      } else if (MODE == 1){
        int R = bx*64 + rloc;
        addr = R*128 + col;
        val = fast_exp2(C2L*val);
      } else {
        int b_ = bx >> 1, i_ = (bx & 1)*64 + rloc;
        addr = b_*16384 + i_*128 + col;
        val = fast_exp2(C2L*val);
      }
      Cout[addr] = val;
    }
  }
}

// ---------------- recurrence ----------------
// grid 256 x 512 thr; block handles batches 2*blk, 2*blk+1.
// Thread (j, beta) holds Wh[:, j] as 128 packed f16 pairs in VGPRs.
// xw[t+1] prefetched ahead of the dot chain; H written as f16.
__global__ __launch_bounds__(512) void k_rnn(const float* __restrict__ h0,
    const float* __restrict__ Wh, const float* __restrict__ xw,
    hf* __restrict__ Hb){
  __shared__ alignas(16) hf h_s[2][2][256];  // [parity][beta][j]
  const int tid = threadIdx.x;
  const int j = tid & 255, beta = tid >> 8;
  const int bb = blockIdx.x*2 + beta;
  hf2 wreg[128];
  #pragma unroll
  for (int m=0;m<128;m++){
    float w0 = Wh[(2*m)*256 + j];
    float w1 = Wh[(2*m+1)*256 + j];
    wreg[m] = (hf2){(hf)w0, (hf)w1};
  }
  h_s[0][beta][j] = (hf)h0[bb*256 + j];
  float z = xw[(0*512 + bb)*256 + j];
  __syncthreads();
  for (int t=0;t<128;t++){
    int p = t & 1;
    float zn = (t < 127) ? xw[((t+1)*512 + bb)*256 + j] : 0.f;
    const hf2* hp = (const hf2*)(&h_s[p][beta][0]);
    float a0=0.f,a1=0.f,a2=0.f,a3=0.f;
    #pragma unroll
    for (int m=0;m<128;m+=4){
      a0 = dot2f(wreg[m],   hp[m],   a0);
      a1 = dot2f(wreg[m+1], hp[m+1], a1);
      a2 = dot2f(wreg[m+2], hp[m+2], a2);
      a3 = dot2f(wreg[m+3], hp[m+3], a3);
    }
    float v = z + ((a0+a1)+(a2+a3));
    float e2 = fast_exp2(v*C2L);
    float hn = 1.f - 2.f*fast_rcp(e2 + 1.f);
    Hb[(t*512+bb)*256 + j] = (hf)hn;
    h_s[p^1][beta][j] = (hf)hn;
    z = zn;
    __syncthreads();
  }
}

// ---------------- attention + softmax + scale ----------------
// grid (512 b, 4 t-tiles), 256 threads. P row halves in registers (64 f32),
// Q tile (32 t) in LDS. Inner element: rcp(fma(P,Q,1)) + fma. No max in
// softmax (|e| <= sum|wv| ~ 5). 2 barriers per 2 timesteps (parity buffers).
__global__ __launch_bounds__(256, 4) void k_attn(const float* __restrict__ P,
    const float* __restrict__ Qm, const float* __restrict__ Wv,
    const float* __restrict__ data, float* __restrict__ out){
  __shared__ alignas(16) float qs[32*128];        // [tt][tau] 16KB
  __shared__ alignas(16) float wvs[128];
  __shared__ alignas(16) float epart[2][2][2][128]; // [parity][tpar][hl][i]
  __shared__ float red[2][2][2];                    // [parity][tpar][half]
  const int b = blockIdx.x, tile = blockIdx.y;
  const int tid = threadIdx.x;
  const int i = tid & 127, hl = tid >> 7;
  const int t0 = tile*32;
  if (tid < 128) wvs[tid] = -2.f*Wv[tid];
  #pragma unroll
  for (int v=0; v<4; v++){
    int flat = v*1024 + tid*4;
    int tt = flat >> 7, c = flat & 127;
    *(float4*)&qs[flat] = *(const float4*)&Qm[((t0+tt)*512 + b)*128 + c];
  }
  float4 p4[16];
  const float* prow = P + b*16384 + i*128 + hl*64;
  #pragma unroll
  for (int v=0; v<16; v++) p4[v] = *(const float4*)&prow[v*4];
  __syncthreads();
  for (int tp=0; tp<16; tp++){
    const int pp = tp & 1;
    const float* q0r = &qs[(2*tp)*128   + hl*64];
    const float* q1r = &qs[(2*tp+1)*128 + hl*64];
    const float* wvr = &wvs[hl*64];
    float4 acc0 = {0.f,0.f,0.f,0.f}, acc1 = {0.f,0.f,0.f,0.f};
    #pragma unroll
    for (int m=0; m<16; m++){
      float4 Pv = p4[m];
      float4 q0 = *(const float4*)&q0r[m*4];
      float4 q1 = *(const float4*)&q1r[m*4];
      float4 wv = *(const float4*)&wvr[m*4];
      float r0x = fast_rcp(fmaf(Pv.x, q0.x, 1.f));
      float r0y = fast_rcp(fmaf(Pv.y, q0.y, 1.f));
      float r0z = fast_rcp(fmaf(Pv.z, q0.z, 1.f));
      float r0w = fast_rcp(fmaf(Pv.w, q0.w, 1.f));
      float r1x = fast_rcp(fmaf(Pv.x, q1.x, 1.f));
      float r1y = fast_rcp(fmaf(Pv.y, q1.y, 1.f));
      float r1z = fast_rcp(fmaf(Pv.z, q1.z, 1.f));
      float r1w = fast_rcp(fmaf(Pv.w, q1.w, 1.f));
      acc0.x = fmaf(wv.x, r0x, acc0.x);
      acc0.y = fmaf(wv.y, r0y, acc0.y);
      acc0.z = fmaf(wv.z, r0z, acc0.z);
      acc0.w = fmaf(wv.w, r0w, acc0.w);
      acc1.x = fmaf(wv.x, r1x, acc1.x);
      acc1.y = fmaf(wv.y, r1y, acc1.y);
      acc1.z = fmaf(wv.z, r1z, acc1.z);
      acc1.w = fmaf(wv.w, r1w, acc1.w);
    }
    epart[pp][0][hl][i] = (acc0.x+acc0.y)+(acc0.z+acc0.w);
    epart[pp][1][hl][i] = (acc1.x+acc1.y)+(acc1.z+acc1.w);
    __syncthreads();
    const int tpar = tid >> 7;
    float e = epart[pp][tpar][0][i] + epart[pp][tpar][1][i];
    float pexp = fast_exp2(e*L2E);
    float sm = pexp;
    #pragma unroll
    for (int off=32; off; off>>=1) sm += __shfl_xor(sm, off);
    if ((tid & 63) == 0) red[pp][tpar][(tid>>6)&1] = sm;
    __syncthreads();
    float ssum = red[pp][tpar][0] + red[pp][tpar][1];
    float alpha = pexp * fast_rcp(ssum);
    int t = t0 + 2*tp + tpar;
    int base = (t*512 + b)*128 + i;
    out[base] = data[base]*alpha;
  }
}

extern "C" void kernel_launch(void* const* d_in, const int* in_sizes, int n_in,
                              void* d_out, int out_size, void* d_ws, size_t ws_size,
                              hipStream_t stream) {
  const float* data = (const float*)d_in[0];
  const float* h0   = (const float*)d_in[1];
  const float* Wx   = (const float*)d_in[2];
  const float* Wh   = (const float*)d_in[3];
  const float* bb   = (const float*)d_in[4];
  const float* W1   = (const float*)d_in[5];
  const float* b1   = (const float*)d_in[6];
  const float* W2   = (const float*)d_in[7];
  const float* b2   = (const float*)d_in[8];
  const float* Wv   = (const float*)d_in[9];
  // d_in[10] = bv: softmax-invariant constant, dropped. d_in[11] = n (128).
  float* wsp = (float*)d_ws;
  float* P   = wsp;                         //  8,388,608 f
  float* xwQ = wsp + 8388608;               // 16,777,216 f (xw, then reused as Q)
  hf*    Hbf = (hf*)(wsp + 25165824);       // 16,777,216 hf
  hf*    wts = (hf*)(wsp + 33554432);       // 81,920 hf
  const hf* Wxt = wts;                      // [256][128]
  const hf* W2t = wts + 32768;              // [128][256]
  const hf* W1t = wts + 65536;              // [128][128]
  float* out = (float*)d_out;

  hipLaunchKernelGGL(k_prep_w, dim3(320), dim3(256), 0, stream, Wx, W2, W1, wts);
  hipLaunchKernelGGL((k_gemm<128,0>), dim3(1024,2), dim3(256), 0, stream,
                     (const void*)data, Wxt, bb, xwQ);
  hipLaunchKernelGGL((k_gemm<128,2>), dim3(1024),   dim3(256), 0, stream,
                     (const void*)data, W1t, b1, P);
  hipLaunchKernelGGL(k_rnn, dim3(256), dim3(512), 0, stream, h0, Wh, xwQ, Hbf);
  hipLaunchKernelGGL((k_gemm<256,1>), dim3(1024),   dim3(256), 0, stream,
                     (const void*)Hbf, W2t, b2, xwQ);
  hipLaunchKernelGGL(k_attn, dim3(512, 4), dim3(256), 0, stream, P, xwQ, Wv, data, out);
}

// Round 4
// 385.483 us; speedup vs baseline: 1.9111x; 1.0356x over previous
//
#include <hip/hip_runtime.h>

// Encoder: B=512, T=128, N=128, H=256
// Round 4: k_attn pairs tau-elements (1 rcp per 2 el) + 4-t inner tile;
//          k_rnn decoupled to 1 batch/block (512 blocks x 256 thr).
//  k_prep_w: Wxt[256][128], W2t[128][256], W1t[128][128] (f16, [n][k] layouts)
//  k_gemm<K,MODE>: C = A @ Bt^T via mfma_f32_16x16x32_f16, Mt=64, Nt=128.
//  k_rnn : h_t = tanh(xw + h@Wh); Wh cols in VGPRs (f16 dot2); writes Hb f16
//  k_attn: e_i = sum_tau (-2wv)*rcp(P*Q+1) (+ softmax-invariant const, dropped)
//          pairwise: w0/u+w1/v = (w0 v + w1 u)*rcp(u v); softmax over i; scale.
// Workspace (f32 offsets): P 0 | xw/Q 8388608 | Hb(hf) 25165824 | wts(hf) 33554432
//   => 134,381,568 bytes.

#define C2L 2.8853900817779268f   // 2*log2(e)
#define L2E 1.4426950408889634f   // log2(e)

typedef _Float16 hf;
typedef _Float16 hf2 __attribute__((ext_vector_type(2)));
typedef _Float16 hf4 __attribute__((ext_vector_type(4)));
typedef _Float16 hf8 __attribute__((ext_vector_type(8)));
typedef float f32x4 __attribute__((ext_vector_type(4)));

__device__ __forceinline__ float fast_exp2(float x){
#if __has_builtin(__builtin_amdgcn_exp2f)
  return __builtin_amdgcn_exp2f(x);
#else
  return exp2f(x);
#endif
}
__device__ __forceinline__ float fast_rcp(float x){
#if __has_builtin(__builtin_amdgcn_rcpf)
  return __builtin_amdgcn_rcpf(x);
#else
  return 1.f/x;
#endif
}
__device__ __forceinline__ float dot2f(hf2 a, hf2 b, float c){
#if __has_builtin(__builtin_amdgcn_fdot2)
  return __builtin_amdgcn_fdot2(a, b, c, false);
#else
  return c + (float)a.x*(float)b.x + (float)a.y*(float)b.y;
#endif
}

// ---------------- weight prep: f32 [k][n] -> f16 [n][k] ----------------
__global__ __launch_bounds__(256) void k_prep_w(const float* __restrict__ Wx,
    const float* __restrict__ W2, const float* __restrict__ W1,
    hf* __restrict__ wts){
  int tid = blockIdx.x*256 + threadIdx.x;   // 320 blocks -> 81920 threads
  if (tid < 32768){                          // Wxt[n<256][k<128]
    int n = tid >> 7, k = tid & 127;
    wts[tid] = (hf)Wx[k*256 + n];
  } else if (tid < 65536){                   // W2t[n<128][k<256]
    int t2 = tid - 32768;
    int n = t2 >> 8, k = t2 & 255;
    wts[tid] = (hf)W2[k*128 + n];
  } else {                                   // W1t[n<128][k<128]
    int t3 = tid - 65536;
    int n = t3 >> 7, k = t3 & 127;
    wts[tid] = (hf)W1[k*128 + n];
  }
}

// ---------------- unified MFMA GEMM ----------------
// block = 256 thr (4 waves). Tile: M=64 (wave strip 16), N=128, K chunked by 128.
// LDS: As[64][136] + Bs[128][136] f16 = 52,224 B.
template<int K, int MODE>
__global__ __launch_bounds__(256) void k_gemm(const void* __restrict__ Asrc,
    const hf* __restrict__ Bt, const float* __restrict__ bias,
    float* __restrict__ Cout){
  constexpr int SA = 136;
  __shared__ alignas(16) hf As[64*SA];
  __shared__ alignas(16) hf Bs[128*SA];
  const int tid = threadIdx.x;
  const int w = tid >> 6, lane = tid & 63;
  const int c = lane & 15, q = lane >> 4;
  const int bx = blockIdx.x;
  const int col0 = (MODE==0) ? blockIdx.y*128 : 0;

  float br[8];
  #pragma unroll
  for (int ni=0; ni<8; ni++) br[ni] = bias[col0 + ni*16 + c];

  f32x4 acc[8];
  #pragma unroll
  for (int ni=0; ni<8; ni++) acc[ni] = (f32x4){0.f,0.f,0.f,0.f};

  for (int kc=0; kc<K/128; kc++){
    // ---- stage A chunk (64 rows x 128 k) ----
    if (MODE == 0){
      const float* A = (const float*)Asrc + (long)bx*64*128;
      #pragma unroll
      for (int v=0; v<8; v++){
        int f4 = v*256 + tid;
        int m = f4 >> 5, k4 = (f4 & 31)*4;
        float4 d = *(const float4*)&A[m*128 + k4];
        hf4 h = {(hf)d.x,(hf)d.y,(hf)d.z,(hf)d.w};
        *(hf4*)&As[m*SA + k4] = h;
      }
    } else if (MODE == 1){
      const hf* A = (const hf*)Asrc + (long)bx*64*256;
      #pragma unroll
      for (int v=0; v<4; v++){
        int f8 = v*256 + tid;
        int m = f8 >> 4, k8 = (f8 & 15)*8;
        *(hf8*)&As[m*SA + k8] = *(const hf8*)&A[m*256 + kc*128 + k8];
      }
    } else {
      const float* A = (const float*)Asrc + (long)(bx>>1)*16384;
      const int i0 = (bx & 1)*64;
      #pragma unroll
      for (int v=0; v<8; v++){
        int f4 = v*256 + tid;
        int t = f4 >> 4, i4 = (f4 & 15)*4;
        float4 d = *(const float4*)&A[t*128 + i0 + i4];
        As[(i4+0)*SA + t] = (hf)d.x;
        As[(i4+1)*SA + t] = (hf)d.y;
        As[(i4+2)*SA + t] = (hf)d.z;
        As[(i4+3)*SA + t] = (hf)d.w;
      }
    }
    // ---- stage B chunk (128 n x 128 k), Bt is f16 [n][K] ----
    #pragma unroll
    for (int v=0; v<8; v++){
      int f8 = v*256 + tid;
      int n = f8 >> 4, k8 = (f8 & 15)*8;
      *(hf8*)&Bs[n*SA + k8] = *(const hf8*)&Bt[(col0+n)*K + kc*128 + k8];
    }
    __syncthreads();
    // ---- MFMA ----
    #pragma unroll
    for (int kk=0; kk<4; kk++){
      hf8 a = *(const hf8*)&As[(w*16 + c)*SA + kk*32 + q*8];
      #pragma unroll
      for (int ni=0; ni<8; ni++){
        hf8 b = *(const hf8*)&Bs[(ni*16 + c)*SA + kk*32 + q*8];
        acc[ni] = __builtin_amdgcn_mfma_f32_16x16x32_f16(a, b, acc[ni], 0, 0, 0);
      }
    }
    __syncthreads();
  }
  // ---- epilogue ----
  #pragma unroll
  for (int ni=0; ni<8; ni++){
    #pragma unroll
    for (int r=0; r<4; r++){
      int rloc = w*16 + q*4 + r;
      int col = col0 + ni*16 + c;
      float val = acc[ni][r] + br[ni];
      int addr;
      if (MODE == 0){
        int R = bx*64 + rloc;
        int b_ = R >> 7, t_ = R & 127;
        addr = (t_*512 + b_)*256 + col;
      } else if (MODE == 1){
        int R = bx*64 + rloc;
        addr = R*128 + col;
        val = fast_exp2(C2L*val);
      } else {
        int b_ = bx >> 1, i_ = (bx & 1)*64 + rloc;
        addr = b_*16384 + i_*128 + col;
        val = fast_exp2(C2L*val);
      }
      Cout[addr] = val;
    }
  }
}

// ---------------- recurrence ----------------
// grid 512 x 256 thr; block owns ONE batch (no cross-batch barrier coupling).
// Thread j holds Wh[:, j] as 128 packed f16 pairs in VGPRs (~160 VGPR ->
// 3 waves/SIMD -> 12 waves/CU). h broadcast from LDS as hf8 chunks; 8 acc
// chains; xw[t+1] prefetched; H written f16.
__global__ __launch_bounds__(256, 3) void k_rnn(const float* __restrict__ h0,
    const float* __restrict__ Wh, const float* __restrict__ xw,
    hf* __restrict__ Hb){
  __shared__ alignas(16) hf h_s[2][256];  // [parity][j]
  const int j = threadIdx.x;
  const int bb = blockIdx.x;
  hf2 wreg[128];
  #pragma unroll
  for (int m=0;m<128;m++){
    float w0 = Wh[(2*m)*256 + j];
    float w1 = Wh[(2*m+1)*256 + j];
    wreg[m] = (hf2){(hf)w0, (hf)w1};
  }
  h_s[0][j] = (hf)h0[bb*256 + j];
  float z = xw[(0*512 + bb)*256 + j];
  __syncthreads();
  for (int t=0;t<128;t++){
    int p = t & 1;
    float zn = (t < 127) ? xw[((t+1)*512 + bb)*256 + j] : 0.f;
    const hf8* h8 = (const hf8*)(&h_s[p][0]);   // 32 chunks of 8 halfs
    float a[8];
    #pragma unroll
    for (int u=0;u<8;u++) a[u]=0.f;
    #pragma unroll
    for (int mm=0; mm<32; mm++){
      hf8 hv = h8[mm];
      hf2 h0p = {hv[0],hv[1]}, h1p = {hv[2],hv[3]};
      hf2 h2p = {hv[4],hv[5]}, h3p = {hv[6],hv[7]};
      a[(4*mm+0)&7] = dot2f(wreg[4*mm+0], h0p, a[(4*mm+0)&7]);
      a[(4*mm+1)&7] = dot2f(wreg[4*mm+1], h1p, a[(4*mm+1)&7]);
      a[(4*mm+2)&7] = dot2f(wreg[4*mm+2], h2p, a[(4*mm+2)&7]);
      a[(4*mm+3)&7] = dot2f(wreg[4*mm+3], h3p, a[(4*mm+3)&7]);
    }
    float v = z + (((a[0]+a[1])+(a[2]+a[3])) + ((a[4]+a[5])+(a[6]+a[7])));
    float e2 = fast_exp2(v*C2L);
    float hn = 1.f - 2.f*fast_rcp(e2 + 1.f);
    Hb[(t*512+bb)*256 + j] = (hf)hn;
    h_s[p^1][j] = (hf)hn;
    z = zn;
    __syncthreads();
  }
}

// ---------------- attention + softmax + scale ----------------
// grid (512 b, 4 t-tiles), 256 threads. P row halves in registers (64 f32),
// Q tile (32 t) in LDS. Pairwise rcp: w0/u+w1/v = (w0 v + w1 u)*rcp(u*v)
// -> 1 rcp per 2 elements. 4 timesteps per sweep. No max in softmax
// (|e| <= sum|wv| ~ 5). 2 barriers per 4 timesteps (parity buffers).
__global__ __launch_bounds__(256, 4) void k_attn(const float* __restrict__ P,
    const float* __restrict__ Qm, const float* __restrict__ Wv,
    const float* __restrict__ data, float* __restrict__ out){
  __shared__ alignas(16) float qs[32*128];          // [tt][tau] 16KB
  __shared__ alignas(16) float wvs[128];
  __shared__ alignas(16) float epart[2][2][4][128]; // [parity][hl][tl][i] 16KB
  __shared__ float red[2][4][2];                    // [parity][tl][half]
  const int b = blockIdx.x, tile = blockIdx.y;
  const int tid = threadIdx.x;
  const int i = tid & 127, hl = tid >> 7;
  const int t0 = tile*32;
  if (tid < 128) wvs[tid] = -2.f*Wv[tid];
  #pragma unroll
  for (int v=0; v<4; v++){
    int flat = v*1024 + tid*4;
    int tt = flat >> 7, c = flat & 127;
    *(float4*)&qs[flat] = *(const float4*)&Qm[((t0+tt)*512 + b)*128 + c];
  }
  float4 p4[16];
  const float* prow = P + b*16384 + i*128 + hl*64;
  #pragma unroll
  for (int v=0; v<16; v++) p4[v] = *(const float4*)&prow[v*4];
  __syncthreads();
  for (int tp=0; tp<8; tp++){
    const int pp = tp & 1;
    const float* q0r = &qs[(4*tp)*128   + hl*64];
    const float* q1r = &qs[(4*tp+1)*128 + hl*64];
    const float* q2r = &qs[(4*tp+2)*128 + hl*64];
    const float* q3r = &qs[(4*tp+3)*128 + hl*64];
    const float* wvr = &wvs[hl*64];
    float acc0=0.f, acc1=0.f, acc2=0.f, acc3=0.f;
    #pragma unroll
    for (int m=0; m<16; m++){
      float4 Pv = p4[m];
      float4 wv = *(const float4*)&wvr[m*4];
      {
        float4 qq = *(const float4*)&q0r[m*4];
        float u = fmaf(Pv.x, qq.x, 1.f), v = fmaf(Pv.y, qq.y, 1.f);
        float n = fmaf(wv.x, v, wv.y*u);
        acc0 = fmaf(n, fast_rcp(u*v), acc0);
        float u2 = fmaf(Pv.z, qq.z, 1.f), v2 = fmaf(Pv.w, qq.w, 1.f);
        float n2 = fmaf(wv.z, v2, wv.w*u2);
        acc0 = fmaf(n2, fast_rcp(u2*v2), acc0);
      }
      {
        float4 qq = *(const float4*)&q1r[m*4];
        float u = fmaf(Pv.x, qq.x, 1.f), v = fmaf(Pv.y, qq.y, 1.f);
        float n = fmaf(wv.x, v, wv.y*u);
        acc1 = fmaf(n, fast_rcp(u*v), acc1);
        float u2 = fmaf(Pv.z, qq.z, 1.f), v2 = fmaf(Pv.w, qq.w, 1.f);
        float n2 = fmaf(wv.z, v2, wv.w*u2);
        acc1 = fmaf(n2, fast_rcp(u2*v2), acc1);
      }
      {
        float4 qq = *(const float4*)&q2r[m*4];
        float u = fmaf(Pv.x, qq.x, 1.f), v = fmaf(Pv.y, qq.y, 1.f);
        float n = fmaf(wv.x, v, wv.y*u);
        acc2 = fmaf(n, fast_rcp(u*v), acc2);
        float u2 = fmaf(Pv.z, qq.z, 1.f), v2 = fmaf(Pv.w, qq.w, 1.f);
        float n2 = fmaf(wv.z, v2, wv.w*u2);
        acc2 = fmaf(n2, fast_rcp(u2*v2), acc2);
      }
      {
        float4 qq = *(const float4*)&q3r[m*4];
        float u = fmaf(Pv.x, qq.x, 1.f), v = fmaf(Pv.y, qq.y, 1.f);
        float n = fmaf(wv.x, v, wv.y*u);
        acc3 = fmaf(n, fast_rcp(u*v), acc3);
        float u2 = fmaf(Pv.z, qq.z, 1.f), v2 = fmaf(Pv.w, qq.w, 1.f);
        float n2 = fmaf(wv.z, v2, wv.w*u2);
        acc3 = fmaf(n2, fast_rcp(u2*v2), acc3);
      }
    }
    epart[pp][hl][0][i] = acc0;
    epart[pp][hl][1][i] = acc1;
    epart[pp][hl][2][i] = acc2;
    epart[pp][hl][3][i] = acc3;
    __syncthreads();
    const int g = tid >> 7;    // 0/1
    float pe[2];
    #pragma unroll
    for (int s=0; s<2; s++){
      int tl = g + 2*s;        // g=0 -> t 0,2 ; g=1 -> t 1,3
      float e = epart[pp][0][tl][i] + epart[pp][1][tl][i];
      pe[s] = fast_exp2(e*L2E);
      float sm = pe[s];
      #pragma unroll
      for (int off=32; off; off>>=1) sm += __shfl_xor(sm, off);
      if ((tid & 63) == 0) red[pp][tl][(tid>>6)&1] = sm;
    }
    __syncthreads();
    #pragma unroll
    for (int s=0; s<2; s++){
      int tl = g + 2*s;
      float ssum = red[pp][tl][0] + red[pp][tl][1];
      float alpha = pe[s] * fast_rcp(ssum);
      int t = t0 + 4*tp + tl;
      int base = (t*512 + b)*128 + i;
      out[base] = data[base]*alpha;
    }
  }
}

extern "C" void kernel_launch(void* const* d_in, const int* in_sizes, int n_in,
                              void* d_out, int out_size, void* d_ws, size_t ws_size,
                              hipStream_t stream) {
  const float* data = (const float*)d_in[0];
  const float* h0   = (const float*)d_in[1];
  const float* Wx   = (const float*)d_in[2];
  const float* Wh   = (const float*)d_in[3];
  const float* bb   = (const float*)d_in[4];
  const float* W1   = (const float*)d_in[5];
  const float* b1   = (const float*)d_in[6];
  const float* W2   = (const float*)d_in[7];
  const float* b2   = (const float*)d_in[8];
  const float* Wv   = (const float*)d_in[9];
  // d_in[10] = bv: softmax-invariant constant, dropped. d_in[11] = n (128).
  float* wsp = (float*)d_ws;
  float* P   = wsp;                         //  8,388,608 f
  float* xwQ = wsp + 8388608;               // 16,777,216 f (xw, then reused as Q)
  hf*    Hbf = (hf*)(wsp + 25165824);       // 16,777,216 hf
  hf*    wts = (hf*)(wsp + 33554432);       // 81,920 hf
  const hf* Wxt = wts;                      // [256][128]
  const hf* W2t = wts + 32768;              // [128][256]
  const hf* W1t = wts + 65536;              // [128][128]
  float* out = (float*)d_out;

  hipLaunchKernelGGL(k_prep_w, dim3(320), dim3(256), 0, stream, Wx, W2, W1, wts);
  hipLaunchKernelGGL((k_gemm<128,0>), dim3(1024,2), dim3(256), 0, stream,
                     (const void*)data, Wxt, bb, xwQ);
  hipLaunchKernelGGL((k_gemm<128,2>), dim3(1024),   dim3(256), 0, stream,
                     (const void*)data, W1t, b1, P);
  hipLaunchKernelGGL(k_rnn, dim3(512), dim3(256), 0, stream, h0, Wh, xwQ, Hbf);
  hipLaunchKernelGGL((k_gemm<256,1>), dim3(1024),   dim3(256), 0, stream,
                     (const void*)Hbf, W2t, b2, xwQ);
  hipLaunchKernelGGL(k_attn, dim3(512, 4), dim3(256), 0, stream, P, xwQ, Wv, data, out);
}